// Round 3
// baseline (85.063 us; speedup 1.0000x reference)
//
#include <hip/hip_runtime.h>

#define S_LEN 2048
#define D_DIM 256
#define WIN 33
#define HALF 16
#define TROWS 32
#define FRAME 64        // k-rows s0-16 .. s0+47; every frame col is in-band for some row
#define SC_STRIDE 68    // f32
#define PT_STRIDE 72    // shorts; row pitch 144 B -> b128 frag reads 16B-aligned

typedef __attribute__((ext_vector_type(8))) short short8_t;
typedef __attribute__((ext_vector_type(4))) float f32x4;

// two f32 -> packed bf16x2, round-half-away: 2 adds + 1 v_perm
__device__ inline unsigned pack2_bf16(float lo, float hi) {
    unsigned a = __float_as_uint(lo) + 0x8000u;
    unsigned b = __float_as_uint(hi) + 0x8000u;
    return __builtin_amdgcn_perm(b, a, 0x07060302);
}
__device__ inline short8_t pack_bf16x8(float4 x, float4 y) {
    union { unsigned u[4]; short8_t s; } r;
    r.u[0] = pack2_bf16(x.x, x.y); r.u[1] = pack2_bf16(x.z, x.w);
    r.u[2] = pack2_bf16(y.x, y.y); r.u[3] = pack2_bf16(y.z, y.w);
    return r.s;
}

// LDS-only barrier: drains ds ops (lgkmcnt) but leaves register-destined
// global loads (vmcnt) in flight across the barrier.
__device__ inline void lds_barrier() {
    asm volatile("s_waitcnt lgkmcnt(0)\n\ts_barrier" ::: "memory");
}

// v10: 32-row tile, 64-row K/V frame, 256 blocks x 1024 threads (16 waves).
// Halves K/V HBM redundancy (3x -> 2x, ~68 MB -> ~52 MB total) and uses ALL
// 16 waves in every phase: QK = 8 16x16 tiles x 2-way split-K (wave w ->
// tile w>>1, K-half w&1, 4 ks-steps); PV = 16-wide d-slice per wave, 2 row
// tiles sharing one B-frag pair. V operands preloaded to regs pre-barrier
// (vmcnt in flight across softmax), bf16 pack deferred to PV.
__global__ __launch_bounds__(1024, 4) void local_attn_v10(
    const float* __restrict__ q,
    const float* __restrict__ k,
    const float* __restrict__ v,
    const int*   __restrict__ mask,
    float* __restrict__ out_v,   // [B*S*D]
    float* __restrict__ out_p)   // [B*S*WIN]
{
    __shared__ __align__(16) float          Sc[2][TROWS * SC_STRIDE];  // 17.4 KB
    __shared__ __align__(16) unsigned short Pt[TROWS * PT_STRIDE];     // 4.6 KB
    __shared__ int wm[FRAME];

    const int t    = threadIdx.x;
    const int lane = t & 63;
    const int w    = t >> 6;          // wave 0..15
    const int l15  = lane & 15;
    const int q4   = lane >> 4;

    const int bid  = blockIdx.x;                      // 0..255
    const int tile = ((bid & 7) << 5) | (bid >> 3);   // XCD-contiguous stripes
    const int b    = tile >> 6;                       // 64 tiles per batch
    const int ts   = tile & 63;
    const int s0   = ts << 5;                         // first query row
    const bool interior = (ts >= 1) && (ts <= 62);    // frame rows all in [0,S)

    const float* qb = q + ((size_t)b * S_LEN + s0) * D_DIM;
    const float* kb = k + (size_t)b * S_LEN * D_DIM;
    const float* vb = v + (size_t)b * S_LEN * D_DIM;

    if (t < FRAME) {
        const int idx = s0 - HALF + t;
        wm[t] = (idx >= 0 && idx < S_LEN) ? (mask[b * S_LEN + idx] != 0) : 0;
    }

    // QK decomposition: tile tt = w>>1 (rt = tt>>2 row-tile, ct = tt&3
    // col-tile), K-half h = w&1 (ks = 4h..4h+3).
    const int tt = w >> 1;
    const int h  = w & 1;
    const int rt = tt >> 2;
    const int ct = tt & 3;
    const int c  = 16 * ct + l15;                     // frame col 0..63

    // PV V-operand staging: wave w owns d-slice [16w, 16w+16).
    // bv[ks][j] = V[g = ks*32 + q4*8 + j][d = 16w + l15], ks = 0..1.
    float vr[2][8];

    if (interior) {
        // ---- Phase A1: QK partial (4 ks-steps), no clamps ----
        {
            const float* kr = kb + (size_t)(s0 - HALF + c) * D_DIM;
            const float* qr = qb + (size_t)(16 * rt + l15) * D_DIM;
            f32x4 acc = (f32x4){0.f, 0.f, 0.f, 0.f};
#pragma unroll
            for (int i = 0; i < 4; ++i) {
                const int ks = 4 * h + i;
                const float* pq = qr + ks * 32 + q4 * 8;
                const float* pk = kr + ks * 32 + q4 * 8;
                const short8_t aq = pack_bf16x8(*(const float4*)pq, *(const float4*)(pq + 4));
                const short8_t bk = pack_bf16x8(*(const float4*)pk, *(const float4*)(pk + 4));
                acc = __builtin_amdgcn_mfma_f32_16x16x32_bf16(aq, bk, acc, 0, 0, 0);
            }
#pragma unroll
            for (int r = 0; r < 4; ++r)
                Sc[h][(16 * rt + q4 * 4 + r) * SC_STRIDE + c] = acc[r];
        }
        // ---- Phase A2: issue V loads (clamp-free, imm offsets) ----
        const float* pv = vb + (size_t)(s0 - HALF + q4 * 8) * D_DIM + 16 * w + l15;
#pragma unroll
        for (int j = 0; j < 8; ++j)
            vr[0][j] = pv[(size_t)j * D_DIM];
        const float* pv1 = pv + (size_t)32 * D_DIM;
#pragma unroll
        for (int j = 0; j < 8; ++j)
            vr[1][j] = pv1[(size_t)j * D_DIM];
    } else {
        // ---- Boundary tiles (8 of 256): generic clamped path ----
        {
            const int kidx = min(max(s0 - HALF + c, 0), S_LEN - 1);
            const float* kr = kb + (size_t)kidx * D_DIM;
            const float* qr = qb + (size_t)(16 * rt + l15) * D_DIM;
            f32x4 acc = (f32x4){0.f, 0.f, 0.f, 0.f};
#pragma unroll
            for (int i = 0; i < 4; ++i) {
                const int ks = 4 * h + i;
                const float* pq = qr + ks * 32 + q4 * 8;
                const float* pk = kr + ks * 32 + q4 * 8;
                const short8_t aq = pack_bf16x8(*(const float4*)pq, *(const float4*)(pq + 4));
                const short8_t bk = pack_bf16x8(*(const float4*)pk, *(const float4*)(pk + 4));
                acc = __builtin_amdgcn_mfma_f32_16x16x32_bf16(aq, bk, acc, 0, 0, 0);
            }
#pragma unroll
            for (int r = 0; r < 4; ++r)
                Sc[h][(16 * rt + q4 * 4 + r) * SC_STRIDE + c] = acc[r];
        }
        const int d = 16 * w + l15;
#pragma unroll
        for (int ks = 0; ks < 2; ++ks)
#pragma unroll
            for (int j = 0; j < 8; ++j) {
                const int g   = ks * 32 + q4 * 8 + j;
                const int idx = min(max(s0 - HALF + g, 0), S_LEN - 1);
                vr[ks][j] = vb[(size_t)idx * D_DIM + d];
            }
    }

    lds_barrier();   // Sc/wm visible; V loads still in flight (vmcnt)

    // ---- Phase B: softmax, row = t>>5 (0..31), thread covers cols 2e, 2e+1 ----
    {
        const int row = t >> 5;
        const int e   = t & 31;
        float vs[2];
#pragma unroll
        for (int kq = 0; kq < 2; ++kq) {
            const int cc = 2 * e + kq;                  // frame col 0..63
            const int j  = cc - row;                    // window tap
            const bool inb = (j >= 0) && (j < WIN);
            const float sv = (Sc[0][row * SC_STRIDE + cc] + Sc[1][row * SC_STRIDE + cc]) * 0.0625f;
            vs[kq] = inb ? (wm[cc] ? sv : -1e10f) : -1e30f;
        }
        float m = fmaxf(vs[0], vs[1]);
        m = fmaxf(m, __shfl_xor(m, 1, 64));
        m = fmaxf(m, __shfl_xor(m, 2, 64));
        m = fmaxf(m, __shfl_xor(m, 4, 64));
        m = fmaxf(m, __shfl_xor(m, 8, 64));
        m = fmaxf(m, __shfl_xor(m, 16, 64));
        float s = 0.f;
#pragma unroll
        for (int kq = 0; kq < 2; ++kq) { vs[kq] = __expf(vs[kq] - m); s += vs[kq]; }
        s += __shfl_xor(s, 1, 64);
        s += __shfl_xor(s, 2, 64);
        s += __shfl_xor(s, 4, 64);
        s += __shfl_xor(s, 8, 64);
        s += __shfl_xor(s, 16, 64);
        const float rinv = 1.0f / s;

        float p0 = vs[0] * rinv, p1 = vs[1] * rinv;     // exact 0 out-of-band
        *(unsigned*)&Pt[row * PT_STRIDE + 2 * e] = pack2_bf16(p0, p1);
        float* prow = out_p + ((size_t)(b * S_LEN + s0 + row)) * WIN;
        const int j0 = 2 * e - row;
        if (j0 >= 0 && j0 < WIN)         prow[j0]     = p0;
        if (j0 + 1 >= 0 && j0 + 1 < WIN) prow[j0 + 1] = p1;
    }

    lds_barrier();   // Pt visible

    // ---- Phase C: pack V frags (vmcnt waits land here), then PV ----
    // Wave w: d-slice [16w,16w+16), both row-tiles share bv[0..1].
    {
        short8_t bv[2];
#pragma unroll
        for (int ks = 0; ks < 2; ++ks) {
            float4 x, y;
            x.x = vr[ks][0]; x.y = vr[ks][1]; x.z = vr[ks][2]; x.w = vr[ks][3];
            y.x = vr[ks][4]; y.y = vr[ks][5]; y.z = vr[ks][6]; y.w = vr[ks][7];
            bv[ks] = pack_bf16x8(x, y);
        }

        float* ob = out_v + ((size_t)b * S_LEN + s0) * D_DIM;
        const int d = 16 * w + l15;
#pragma unroll
        for (int rr = 0; rr < 2; ++rr) {
            const short8_t ap0 = *(const short8_t*)&Pt[(16 * rr + l15) * PT_STRIDE + q4 * 8];
            const short8_t ap1 = *(const short8_t*)&Pt[(16 * rr + l15) * PT_STRIDE + 32 + q4 * 8];
            f32x4 acc = (f32x4){0.f, 0.f, 0.f, 0.f};
            acc = __builtin_amdgcn_mfma_f32_16x16x32_bf16(ap0, bv[0], acc, 0, 0, 0);
            acc = __builtin_amdgcn_mfma_f32_16x16x32_bf16(ap1, bv[1], acc, 0, 0, 0);
#pragma unroll
            for (int r = 0; r < 4; ++r)
                ob[(size_t)(16 * rr + q4 * 4 + r) * D_DIM + d] = acc[r];
        }
    }
}

extern "C" void kernel_launch(void* const* d_in, const int* in_sizes, int n_in,
                              void* d_out, int out_size, void* d_ws, size_t ws_size,
                              hipStream_t stream) {
    const float* q    = (const float*)d_in[0];
    const float* k    = (const float*)d_in[1];
    const float* v    = (const float*)d_in[2];
    const int*   mask = (const int*)d_in[3];

    const int B = 4;
    float* out_v = (float*)d_out;
    float* out_p = (float*)d_out + (size_t)B * S_LEN * D_DIM;

    const int blocks = B * (S_LEN / TROWS);   // 256 blocks x 1024 threads
    local_attn_v10<<<blocks, 1024, 0, stream>>>(q, k, v, mask, out_v, out_p);
}

// Round 4
// 84.334 us; speedup vs baseline: 1.0086x; 1.0086x over previous
//
#include <hip/hip_runtime.h>

#define S_LEN 2048
#define D_DIM 256
#define WIN 33
#define HALF 16
#define TROWS 16
#define SPAN 48         // cols 48..63 of the 64-wide frame are always out-of-band
#define SC_STRIDE 68    // f32
#define PT_STRIDE 72    // shorts; row pitch 144 B -> b128 frag reads 16B-aligned

typedef __attribute__((ext_vector_type(8))) short short8_t;
typedef __attribute__((ext_vector_type(4))) float f32x4;

__device__ inline unsigned short f32_to_bf16(float f) {
    unsigned u = __float_as_uint(f);
    return (unsigned short)((u + 0x7fffu + ((u >> 16) & 1u)) >> 16);  // RNE
}
// two f32 -> packed bf16x2, round-half-away: 2 adds + 1 v_perm
__device__ inline unsigned pack2_bf16(float lo, float hi) {
    unsigned a = __float_as_uint(lo) + 0x8000u;
    unsigned b = __float_as_uint(hi) + 0x8000u;
    return __builtin_amdgcn_perm(b, a, 0x07060302);
}
__device__ inline short8_t pack_bf16x8(float4 x, float4 y) {
    union { unsigned u[4]; short8_t s; } r;
    r.u[0] = pack2_bf16(x.x, x.y); r.u[1] = pack2_bf16(x.z, x.w);
    r.u[2] = pack2_bf16(y.x, y.y); r.u[3] = pack2_bf16(y.z, y.w);
    return r.s;
}

// v11 == v7 (revert): best-measured variant of this session (82.28 us).
// v8 (occupancy pin + LDS-only barriers), v9 (QK split-K), v10 (32-row tile,
// -24% HBM traffic) were all neutral-to-worse -> dur_us is harness-floor
// dominated; keep the simplest/best kernel.
// 512 blocks x 512 threads (8 waves) = 4096 waves -> 4 waves/SIMD, 2 blocks/CU.
// Tile = 16 query rows, span 48. Waves 0..2: one 16x16 QK tile each (global->
// reg bf16 frags). All waves: preload own PV V-operands (32-wide D-slice) to
// registers pre-barrier. Softmax: 32 threads/row. PV: 2 MFMA per wave.
// Two co-resident blocks/CU interleave phases -> barrier gaps get filled.
__global__ __launch_bounds__(512) void local_attn_v7(
    const float* __restrict__ q,
    const float* __restrict__ k,
    const float* __restrict__ v,
    const int*   __restrict__ mask,
    float* __restrict__ out_v,   // [B*S*D]
    float* __restrict__ out_p)   // [B*S*WIN]
{
    __shared__ __align__(16) float          Sc[TROWS * SC_STRIDE];  // 4.35 KB
    __shared__ __align__(16) unsigned short Pt[TROWS * PT_STRIDE];  // 2.25 KB
    __shared__ int wm[SPAN];

    const int t    = threadIdx.x;
    const int lane = t & 63;
    const int w    = t >> 6;          // wave 0..7
    const int l15  = lane & 15;
    const int q4   = lane >> 4;

    const int bid  = blockIdx.x;                      // 0..511
    const int tile = ((bid & 7) << 6) | (bid >> 3);   // XCD-contiguous stripes
    const int b    = tile >> 7;                       // 128 tiles per batch
    const int s0   = (tile & 127) << 4;               // first query row

    const float* qb = q + ((size_t)b * S_LEN + s0) * D_DIM;
    const float* kb = k + (size_t)b * S_LEN * D_DIM;
    const float* vb = v + (size_t)b * S_LEN * D_DIM;

    if (t < SPAN) {
        const int idx = s0 - HALF + t;
        wm[t] = (idx >= 0 && idx < S_LEN) ? (mask[b * S_LEN + idx] != 0) : 0;
    }

    // ---- Phase A1 (waves 0..2): QK 16x16 tile, col-tile w ----
    if (w < 3) {
        const int c    = 16 * w + l15;                 // span col 0..47
        const int kidx = min(max(s0 - HALF + c, 0), S_LEN - 1);
        const float* kr = kb + (size_t)kidx * D_DIM;
        const float* qr = qb + (size_t)l15 * D_DIM;
        f32x4 acc = (f32x4){0.f, 0.f, 0.f, 0.f};
#pragma unroll
        for (int ks = 0; ks < 8; ++ks) {
            const float* pq = qr + ks * 32 + q4 * 8;
            const float* pk = kr + ks * 32 + q4 * 8;
            const short8_t aq = pack_bf16x8(*(const float4*)pq, *(const float4*)(pq + 4));
            const short8_t bk = pack_bf16x8(*(const float4*)pk, *(const float4*)(pk + 4));
            acc = __builtin_amdgcn_mfma_f32_16x16x32_bf16(aq, bk, acc, 0, 0, 0);
        }
#pragma unroll
        for (int r = 0; r < 4; ++r)
            Sc[(q4 * 4 + r) * SC_STRIDE + c] = acc[r];
    }

    // ---- Phase A2 (all waves): PV V-operand preload, D-slice [32w, 32w+32) ----
    // B-frag[nt][ks][j] = V[g = ks*32 + q4*8 + j][d = 32w + nt*16 + l15]
    // ks=1 with q4>=2 -> g>=48: P=0 there, use zero frag (no load).
    short8_t bv[2][2];
    {
        const bool act1 = (q4 < 2);
        const short8_t zfrag = {0,0,0,0,0,0,0,0};
        float vr[2][2][8];
#pragma unroll
        for (int nt = 0; nt < 2; ++nt) {
            const int d = 32 * w + nt * 16 + l15;
#pragma unroll
            for (int j = 0; j < 8; ++j) {
                const int g0   = q4 * 8 + j;
                const int idx0 = min(max(s0 - HALF + g0, 0), S_LEN - 1);
                vr[nt][0][j] = vb[(size_t)idx0 * D_DIM + d];
            }
            if (act1) {
#pragma unroll
                for (int j = 0; j < 8; ++j) {
                    const int g1   = 32 + q4 * 8 + j;   // < 48 when q4 < 2
                    const int idx1 = min(max(s0 - HALF + g1, 0), S_LEN - 1);
                    vr[nt][1][j] = vb[(size_t)idx1 * D_DIM + d];
                }
            }
        }
#pragma unroll
        for (int nt = 0; nt < 2; ++nt) {
            float4 x, y;
            x.x = vr[nt][0][0]; x.y = vr[nt][0][1]; x.z = vr[nt][0][2]; x.w = vr[nt][0][3];
            y.x = vr[nt][0][4]; y.y = vr[nt][0][5]; y.z = vr[nt][0][6]; y.w = vr[nt][0][7];
            bv[nt][0] = pack_bf16x8(x, y);
            if (act1) {
                x.x = vr[nt][1][0]; x.y = vr[nt][1][1]; x.z = vr[nt][1][2]; x.w = vr[nt][1][3];
                y.x = vr[nt][1][4]; y.y = vr[nt][1][5]; y.z = vr[nt][1][6]; y.w = vr[nt][1][7];
                bv[nt][1] = pack_bf16x8(x, y);
            } else {
                bv[nt][1] = zfrag;
            }
        }
    }
    __syncthreads();

    // ---- Phase B: softmax, row = t>>5 (0..15), thread covers cols 2e, 2e+1 ----
    {
        const int row = t >> 5;
        const int e   = t & 31;
        float vs[2];
#pragma unroll
        for (int kq = 0; kq < 2; ++kq) {
            const int c = 2 * e + kq;                   // frame col 0..63
            const int j = c - row;
            const bool inb = (j >= 0) && (j < WIN) && (c < SPAN);
            vs[kq] = inb ? (wm[c < SPAN ? c : 0] ? Sc[row * SC_STRIDE + (c < SPAN ? c : 0)] * 0.0625f
                                                 : -1e10f)
                         : -1e30f;
        }
        float m = fmaxf(vs[0], vs[1]);
        m = fmaxf(m, __shfl_xor(m, 1, 64));
        m = fmaxf(m, __shfl_xor(m, 2, 64));
        m = fmaxf(m, __shfl_xor(m, 4, 64));
        m = fmaxf(m, __shfl_xor(m, 8, 64));
        m = fmaxf(m, __shfl_xor(m, 16, 64));
        float s = 0.f;
#pragma unroll
        for (int kq = 0; kq < 2; ++kq) { vs[kq] = __expf(vs[kq] - m); s += vs[kq]; }
        s += __shfl_xor(s, 1, 64);
        s += __shfl_xor(s, 2, 64);
        s += __shfl_xor(s, 4, 64);
        s += __shfl_xor(s, 8, 64);
        s += __shfl_xor(s, 16, 64);
        const float rinv = 1.0f / s;

        float p0 = vs[0] * rinv, p1 = vs[1] * rinv;     // exact 0 out-of-band
        *(unsigned*)&Pt[row * PT_STRIDE + 2 * e] = pack2_bf16(p0, p1);
        float* prow = out_p + ((size_t)(b * S_LEN + s0 + row)) * WIN;
        const int j0 = 2 * e - row;
        if (j0 >= 0 && j0 < WIN)     prow[j0]     = p0;
        if (j0 + 1 >= 0 && j0 + 1 < WIN) prow[j0 + 1] = p1;
    }
    __syncthreads();

    // ---- Phase C: PV. Wave w -> 16 rows x D cols [32w, 32w+32) ----
    {
        const short8_t ap0 = *(const short8_t*)&Pt[l15 * PT_STRIDE + q4 * 8];
        const short8_t ap1 = *(const short8_t*)&Pt[l15 * PT_STRIDE + 32 + q4 * 8];
        float* ob = out_v + ((size_t)b * S_LEN + s0) * D_DIM;
#pragma unroll
        for (int nt = 0; nt < 2; ++nt) {
            f32x4 acc = (f32x4){0.f, 0.f, 0.f, 0.f};
            acc = __builtin_amdgcn_mfma_f32_16x16x32_bf16(ap0, bv[nt][0], acc, 0, 0, 0);
            acc = __builtin_amdgcn_mfma_f32_16x16x32_bf16(ap1, bv[nt][1], acc, 0, 0, 0);
            const int d = 32 * w + nt * 16 + l15;
#pragma unroll
            for (int r = 0; r < 4; ++r)
                ob[(size_t)(q4 * 4 + r) * D_DIM + d] = acc[r];
        }
    }
}

extern "C" void kernel_launch(void* const* d_in, const int* in_sizes, int n_in,
                              void* d_out, int out_size, void* d_ws, size_t ws_size,
                              hipStream_t stream) {
    const float* q    = (const float*)d_in[0];
    const float* k    = (const float*)d_in[1];
    const float* v    = (const float*)d_in[2];
    const int*   mask = (const int*)d_in[3];

    const int B = 4;
    float* out_v = (float*)d_out;
    float* out_p = (float*)d_out + (size_t)B * S_LEN * D_DIM;

    const int blocks = B * (S_LEN / TROWS);   // 512 blocks x 512 threads
    local_attn_v7<<<blocks, 512, 0, stream>>>(q, k, v, mask, out_v, out_p);
}